// Round 1
// baseline (168.343 us; speedup 1.0000x reference)
//
#include <hip/hip_runtime.h>
#include <math.h>

#define B   1024
#define IN  1024
#define HID 1024
#define OUT 512
#define T   100

// ---------------------------------------------------------------------------
// ws layout (floats):
//   [0,1024)            delay (in_delay == hid_delay, IN==HID, same slice)
//   [1024,2048)         w1d[b] = sum_h fc1_w[h,b]*delay[h]
//   [2048,2560)         rowsum_fc2[o] = sum_h fc2_w[o,h]
//   [2560]              c1 = sum_h fc1_b[h]*delay[h]
//   [3072,3072+16*1024) w1d partials (16 h-chunks)
//   [20480,20480+T*B)   drive[t*B+b]
//   [20480+T*B, +T)     S[t] = sum_b isp_t[b]*w1d[b] + c1
// total ~ 0.5 MB
// ---------------------------------------------------------------------------

__global__ void k_delay(const float* __restrict__ cd, const float* __restrict__ fc1_b,
                        const float* __restrict__ lorentz,
                        float* __restrict__ delay, float* __restrict__ c1out) {
    __shared__ float part[16];
    int i = threadIdx.x;                       // 1024 threads
    float v = fminf(fmaxf(lorentz[0], 0.0f), 0.999f);
    float gamma = 1.0f / sqrtf(1.0f - v * v);
    float d = expf(-gamma * fabsf(cd[i]) * v);
    delay[i] = d;
    float c = fc1_b[i] * d;
    #pragma unroll
    for (int off = 32; off; off >>= 1) c += __shfl_xor(c, off);
    if ((i & 63) == 0) part[i >> 6] = c;
    __syncthreads();
    if (i == 0) {
        float s = 0.0f;
        #pragma unroll
        for (int k = 0; k < 16; ++k) s += part[k];
        c1out[0] = s;
    }
}

// w1d partials: blockIdx.x = hc*4 + bb ; hc in [0,16) h-chunks of 64, bb in [0,4) b-blocks of 256
__global__ __launch_bounds__(256) void k_w1d_part(const float* __restrict__ fc1_w,
                                                  const float* __restrict__ delay,
                                                  float* __restrict__ partial) {
    int hc = blockIdx.x >> 2;
    int bb = blockIdx.x & 3;
    int b = bb * 256 + threadIdx.x;
    int h0 = hc * 64;
    float acc = 0.0f;
    #pragma unroll 4
    for (int h = h0; h < h0 + 64; ++h)
        acc += fc1_w[h * IN + b] * delay[h];   // consecutive threads -> consecutive addrs
    partial[hc * IN + b] = acc;
}

__global__ __launch_bounds__(256) void k_w1d_combine(const float* __restrict__ partial,
                                                     float* __restrict__ w1d) {
    int b = blockIdx.x * 256 + threadIdx.x;
    float acc = 0.0f;
    #pragma unroll
    for (int c = 0; c < 16; ++c) acc += partial[c * IN + b];
    w1d[b] = acc;
}

// one wave per output row o: rowsum_fc2[o] = sum_h fc2_w[o*HID + h]
__global__ __launch_bounds__(256) void k_rowsum(const float* __restrict__ fc2_w,
                                                float* __restrict__ rowsum) {
    int gwave = (int)((blockIdx.x * 256 + threadIdx.x) >> 6);
    int lane = threadIdx.x & 63;
    if (gwave >= OUT) return;
    const float4* r = (const float4*)(fc2_w + (size_t)gwave * HID);
    float acc = 0.0f;
    #pragma unroll
    for (int k = 0; k < 4; ++k) {
        float4 v = r[k * 64 + lane];
        acc += v.x + v.y + v.z + v.w;
    }
    #pragma unroll
    for (int off = 32; off; off >>= 1) acc += __shfl_xor(acc, off);
    if (lane == 0) rowsum[gwave] = acc;
}

// THE hot kernel: one wave per (b,t) row; drive[t*B+b] = sum_i x[row*IN+i]*delay[i]
__global__ __launch_bounds__(256) void k_drive(const float* __restrict__ x,
                                               const float* __restrict__ delay,
                                               float* __restrict__ drive) {
    int gwave = (int)((blockIdx.x * 256 + threadIdx.x) >> 6);
    int lane = threadIdx.x & 63;
    if (gwave >= B * T) return;
    int b = gwave / T;
    int t = gwave - b * T;
    const float4* xr = (const float4*)(x + (size_t)gwave * IN);
    const float4* dl = (const float4*)delay;
    float acc = 0.0f;
    #pragma unroll
    for (int k = 0; k < 4; ++k) {
        int idx = k * 64 + lane;               // 16B/lane, fully coalesced (1KB/instr)
        float4 xv = xr[idx];
        float4 dv = dl[idx];
        acc += xv.x * dv.x + xv.y * dv.y + xv.z * dv.z + xv.w * dv.w;
    }
    #pragma unroll
    for (int off = 32; off; off >>= 1) acc += __shfl_xor(acc, off);
    if (lane == 0) drive[t * B + b] = acc;
}

// per-batch LIF scan, deterministic block reduction -> S[t]
__global__ __launch_bounds__(1024) void k_scan(const float* __restrict__ drive,
                                               const float* __restrict__ w1d,
                                               const float* __restrict__ c1p,
                                               const float* __restrict__ ibeta,
                                               const float* __restrict__ ithr,
                                               float* __restrict__ S) {
    __shared__ float part[16];
    int b = threadIdx.x;                       // 1024 threads
    int wave = b >> 6, lane = b & 63;
    float ib = ibeta[0], it = ithr[0];
    float c1 = c1p[0];
    float w = w1d[b];
    float im = 0.0f;
    for (int t = 0; t < T; ++t) {
        im = im * ib + drive[t * B + b];
        float isp = (im > it) ? 1.0f : 0.0f;
        im *= (1.0f - isp);
        float c = isp * w;
        #pragma unroll
        for (int off = 32; off; off >>= 1) c += __shfl_xor(c, off);
        if (lane == 0) part[wave] = c;
        __syncthreads();
        if (b == 0) {
            float s = 0.0f;
            #pragma unroll
            for (int k = 0; k < 16; ++k) s += part[k];
            S[t] = s + c1;
        }
        __syncthreads();
    }
}

// scalar hm scan + epilogue
__global__ __launch_bounds__(512) void k_final(const float* __restrict__ S,
                                               const float* __restrict__ rowsum,
                                               const float* __restrict__ fc2_b,
                                               const float* __restrict__ ta,
                                               const float* __restrict__ hbeta,
                                               const float* __restrict__ hthr,
                                               float* __restrict__ out) {
    __shared__ float sw[2];
    if (threadIdx.x == 0) {
        float hb = hbeta[0], ht = hthr[0];
        float hm = 0.0f, wsum = 0.0f, tasum = 0.0f;
        for (int t = 0; t < T; ++t) {
            hm = hm * hb + S[t];
            float hsp = (hm > ht) ? 1.0f : 0.0f;
            hm *= (1.0f - hsp);
            wsum += ta[t] * hsp;
            tasum += ta[t];
        }
        sw[0] = wsum; sw[1] = tasum;
    }
    __syncthreads();
    int o = threadIdx.x;
    if (o < OUT) out[o] = sw[0] * rowsum[o] + sw[1] * fc2_b[o];
}

extern "C" void kernel_launch(void* const* d_in, const int* in_sizes, int n_in,
                              void* d_out, int out_size, void* d_ws, size_t ws_size,
                              hipStream_t stream) {
    const float* x      = (const float*)d_in[0];
    const float* cd     = (const float*)d_in[1];
    const float* fc1_w  = (const float*)d_in[2];
    const float* fc1_b  = (const float*)d_in[3];
    const float* fc2_w  = (const float*)d_in[4];
    const float* fc2_b  = (const float*)d_in[5];
    const float* ta     = (const float*)d_in[6];
    const float* lor    = (const float*)d_in[7];
    const float* ibeta  = (const float*)d_in[8];
    const float* hbeta  = (const float*)d_in[9];
    const float* ithr   = (const float*)d_in[10];
    const float* hthr   = (const float*)d_in[11];
    float* out = (float*)d_out;

    float* wsf     = (float*)d_ws;
    float* delay   = wsf;
    float* w1d     = wsf + 1024;
    float* rowsum  = wsf + 2048;
    float* c1      = wsf + 2560;
    float* partial = wsf + 3072;
    float* drive   = wsf + 20480;
    float* S       = wsf + 20480 + T * B;

    k_delay<<<1, 1024, 0, stream>>>(cd, fc1_b, lor, delay, c1);
    k_w1d_part<<<64, 256, 0, stream>>>(fc1_w, delay, partial);
    k_w1d_combine<<<4, 256, 0, stream>>>(partial, w1d);
    k_rowsum<<<(OUT * 64) / 256, 256, 0, stream>>>(fc2_w, rowsum);
    k_drive<<<(B * T * 64) / 256, 256, 0, stream>>>(x, delay, drive);
    k_scan<<<1, 1024, 0, stream>>>(drive, w1d, c1, ibeta, ithr, S);
    k_final<<<1, 512, 0, stream>>>(S, rowsum, fc2_b, ta, hbeta, hthr, out);
}

// Round 2
// 99.052 us; speedup vs baseline: 1.6995x; 1.6995x over previous
//
#include <hip/hip_runtime.h>
#include <math.h>

#define B   1024
#define IN  1024
#define HID 1024
#define OUT 512
#define T   100

// ---------------------------------------------------------------------------
// ws layout (floats):
//   [0, 16384)            w1d partials (16 h-chunks x 1024 b)
//   [16384, 16896)        rowsum_fc2[o]
//   [16896, 16896+T*B)    drive[t*B+b]
// ---------------------------------------------------------------------------

__device__ __forceinline__ float delay_of(const float* lor, float cdv) {
    float v = fminf(fmaxf(lor[0], 0.0f), 0.999f);
    float g = 1.0f / sqrtf(1.0f - v * v);
    return expf(-g * fabsf(cdv) * v);
}

// blocks 0..63: w1d partials (hc = blk>>2 h-chunk of 64, bb = blk&3 b-block of 256)
// blocks 64..191: fc2 rowsums (one wave per output row)
__global__ __launch_bounds__(256) void k_prep(const float* __restrict__ cd,
                                              const float* __restrict__ fc1_w,
                                              const float* __restrict__ fc2_w,
                                              const float* __restrict__ lor,
                                              float* __restrict__ partial,
                                              float* __restrict__ rowsum) {
    int blk = blockIdx.x;
    if (blk < 64) {
        __shared__ float dly[64];
        int hc = blk >> 2, bb = blk & 3;
        int h0 = hc * 64;
        if (threadIdx.x < 64)
            dly[threadIdx.x] = delay_of(lor, cd[h0 + threadIdx.x]);
        __syncthreads();
        int b = bb * 256 + threadIdx.x;
        float acc = 0.0f;
        #pragma unroll 8
        for (int k = 0; k < 64; ++k)
            acc += fc1_w[(size_t)(h0 + k) * IN + b] * dly[k];   // coalesced across threads
        partial[hc * IN + b] = acc;
    } else {
        int gw = ((blk - 64) * 256 + threadIdx.x) >> 6;          // 512 waves -> OUT rows
        int lane = threadIdx.x & 63;
        const float4* r = (const float4*)(fc2_w + (size_t)gw * HID);
        float acc = 0.0f;
        #pragma unroll
        for (int k = 0; k < 4; ++k) {
            float4 v = r[k * 64 + lane];
            acc += v.x + v.y + v.z + v.w;
        }
        #pragma unroll
        for (int off = 32; off; off >>= 1) acc += __shfl_xor(acc, off);
        if (lane == 0) rowsum[gw] = acc;
    }
}

// hot kernel: one wave per (b,t) row; drive[t*B+b] = sum_i x[row*IN+i]*delay[i]
// delay recomputed per block into LDS (4 expf/thread) -> no dependency on a prep kernel
__global__ __launch_bounds__(256) void k_drive(const float* __restrict__ x,
                                               const float* __restrict__ cd,
                                               const float* __restrict__ lor,
                                               float* __restrict__ drive) {
    __shared__ float dly[IN];
    #pragma unroll
    for (int k = 0; k < 4; ++k) {
        int i = k * 256 + threadIdx.x;
        dly[i] = delay_of(lor, cd[i]);
    }
    __syncthreads();
    int gwave = (int)((blockIdx.x * 256 + threadIdx.x) >> 6);
    int lane = threadIdx.x & 63;
    const float4* xr = (const float4*)(x + (size_t)gwave * IN);
    const float4* dl = (const float4*)dly;
    float acc = 0.0f;
    #pragma unroll
    for (int k = 0; k < 4; ++k) {
        int idx = k * 64 + lane;               // 16B/lane, fully coalesced
        float4 xv = xr[idx];
        float4 dv = dl[idx];
        acc += xv.x * dv.x + xv.y * dv.y + xv.z * dv.z + xv.w * dv.w;
    }
    #pragma unroll
    for (int off = 32; off; off >>= 1) acc += __shfl_xor(acc, off);
    if (lane == 0) {
        int b = gwave / T;
        int t = gwave - b * T;
        drive[t * B + b] = acc;
    }
}

// single block, 1024 threads: c1 + w1d combine + chunked LIF scan + hm scan + output
__global__ __launch_bounds__(1024) void k_scan(const float* __restrict__ drive,
                                               const float* __restrict__ partial,
                                               const float* __restrict__ cd,
                                               const float* __restrict__ fc1_b,
                                               const float* __restrict__ fc2_b,
                                               const float* __restrict__ ta,
                                               const float* __restrict__ lor,
                                               const float* __restrict__ ibeta,
                                               const float* __restrict__ hbeta,
                                               const float* __restrict__ ithr,
                                               const float* __restrict__ hthr,
                                               const float* __restrict__ rowsum,
                                               float* __restrict__ out) {
    __shared__ float cbuf[16][B];   // 64 KB: per-thread spike contributions for 16 t's
    __shared__ float red[16];
    __shared__ float S[T];
    __shared__ float ta_l[T];
    __shared__ float sc[4];         // [0]=c1, [1]=wsum, [2]=tasum
    int b = threadIdx.x, wave = b >> 6, lane = b & 63;

    if (b < T) ta_l[b] = ta[b];

    // c1 = sum_h fc1_b[h] * delay[h]  (block reduction)
    float d = delay_of(lor, cd[b]);
    float c = fc1_b[b] * d;
    #pragma unroll
    for (int off = 32; off; off >>= 1) c += __shfl_xor(c, off);
    if (lane == 0) red[wave] = c;
    __syncthreads();
    if (b == 0) {
        float s = 0.0f;
        #pragma unroll
        for (int k = 0; k < 16; ++k) s += red[k];
        sc[0] = s;
    }
    // (sc[0] visible after the first chunk barrier below)

    // w1d[b] = sum of 16 partials
    float w = 0.0f;
    #pragma unroll
    for (int cc = 0; cc < 16; ++cc) w += partial[cc * IN + b];

    float ib = ibeta[0], it = ithr[0];
    float im = 0.0f;

    // 6 full chunks of 16 timesteps
    for (int t0 = 0; t0 < 96; t0 += 16) {
        #pragma unroll
        for (int tt = 0; tt < 16; ++tt) {
            im = im * ib + drive[(t0 + tt) * B + b];
            float isp = (im > it) ? 1.0f : 0.0f;
            im *= (1.0f - isp);
            cbuf[tt][b] = isp * w;
        }
        __syncthreads();
        {   // wave tt reduces row tt (16 strided LDS reads + 6 shuffles)
            float s = 0.0f;
            #pragma unroll
            for (int k = 0; k < 16; ++k) s += cbuf[wave][lane + 64 * k];
            #pragma unroll
            for (int off = 32; off; off >>= 1) s += __shfl_xor(s, off);
            if (lane == 0) S[t0 + wave] = s + sc[0];
        }
        __syncthreads();
    }
    // tail: 4 timesteps
    {
        #pragma unroll
        for (int tt = 0; tt < 4; ++tt) {
            im = im * ib + drive[(96 + tt) * B + b];
            float isp = (im > it) ? 1.0f : 0.0f;
            im *= (1.0f - isp);
            cbuf[tt][b] = isp * w;
        }
        __syncthreads();
        if (wave < 4) {
            float s = 0.0f;
            #pragma unroll
            for (int k = 0; k < 16; ++k) s += cbuf[wave][lane + 64 * k];
            #pragma unroll
            for (int off = 32; off; off >>= 1) s += __shfl_xor(s, off);
            if (lane == 0) S[96 + wave] = s + sc[0];
        }
        __syncthreads();
    }

    // scalar hm scan
    if (b == 0) {
        float hb = hbeta[0], ht = hthr[0];
        float hm = 0.0f, wsum = 0.0f, tasum = 0.0f;
        for (int t = 0; t < T; ++t) {
            hm = hm * hb + S[t];
            float hsp = (hm > ht) ? 1.0f : 0.0f;
            hm *= (1.0f - hsp);
            wsum += ta_l[t] * hsp;
            tasum += ta_l[t];
        }
        sc[1] = wsum; sc[2] = tasum;
    }
    __syncthreads();
    if (b < OUT) out[b] = sc[1] * rowsum[b] + sc[2] * fc2_b[b];
}

extern "C" void kernel_launch(void* const* d_in, const int* in_sizes, int n_in,
                              void* d_out, int out_size, void* d_ws, size_t ws_size,
                              hipStream_t stream) {
    const float* x      = (const float*)d_in[0];
    const float* cd     = (const float*)d_in[1];
    const float* fc1_w  = (const float*)d_in[2];
    const float* fc1_b  = (const float*)d_in[3];
    const float* fc2_w  = (const float*)d_in[4];
    const float* fc2_b  = (const float*)d_in[5];
    const float* ta     = (const float*)d_in[6];
    const float* lor    = (const float*)d_in[7];
    const float* ibeta  = (const float*)d_in[8];
    const float* hbeta  = (const float*)d_in[9];
    const float* ithr   = (const float*)d_in[10];
    const float* hthr   = (const float*)d_in[11];
    float* out = (float*)d_out;

    float* wsf     = (float*)d_ws;
    float* partial = wsf;
    float* rowsum  = wsf + 16384;
    float* drive   = wsf + 16896;

    k_prep<<<192, 256, 0, stream>>>(cd, fc1_w, fc2_w, lor, partial, rowsum);
    k_drive<<<(B * T) / 4, 256, 0, stream>>>(x, cd, lor, drive);
    k_scan<<<1, 1024, 0, stream>>>(drive, partial, cd, fc1_b, fc2_b, ta, lor,
                                   ibeta, hbeta, ithr, hthr, rowsum, out);
}

// Round 4
// 80.824 us; speedup vs baseline: 2.0828x; 1.2255x over previous
//
#include <hip/hip_runtime.h>
#include <math.h>

#define B   1024
#define IN  1024
#define HID 1024
#define OUT 512
#define T   100

// grid split for k_main
#define NDRV (B * T / 4)        // 25600 blocks, one wave per (b,t) row
#define NW1D 64                 // w1d partial blocks
#define NRSUM 128               // fc2 rowsum blocks

typedef float v4f __attribute__((ext_vector_type(4)));

// ---------------------------------------------------------------------------
// ws layout (floats):
//   [0, 16384)            w1d partials (16 h-chunks x 1024 b)
//   [16384, 16896)        rowsum_fc2[o]
//   [16896, 16896+T*B)    drive[t*B+b]
// ---------------------------------------------------------------------------

__device__ __forceinline__ float delay_of(const float* lor, float cdv) {
    float v = fminf(fmaxf(lor[0], 0.0f), 0.999f);
    float g = 1.0f / sqrtf(1.0f - v * v);
    return expf(-g * fabsf(cdv) * v);
}

// blocks [0, NDRV): drive — one wave per (b,t) row, nontemporal x reads
// blocks [NDRV, NDRV+NW1D): w1d partials (hc = q>>2 h-chunk of 64, bb = q&3)
// blocks [NDRV+NW1D, NDRV+NW1D+NRSUM): fc2 rowsums (one wave per output row)
__global__ __launch_bounds__(256) void k_main(const float* __restrict__ x,
                                              const float* __restrict__ cd,
                                              const float* __restrict__ fc1_w,
                                              const float* __restrict__ fc2_w,
                                              const float* __restrict__ lor,
                                              float* __restrict__ drive,
                                              float* __restrict__ partial,
                                              float* __restrict__ rowsum) {
    int blk = blockIdx.x;
    if (blk < NDRV) {
        __shared__ float dly[IN];
        #pragma unroll
        for (int k = 0; k < 4; ++k) {
            int i = k * 256 + threadIdx.x;
            dly[i] = delay_of(lor, cd[i]);
        }
        __syncthreads();
        int gwave = (int)(((size_t)blk * 256 + threadIdx.x) >> 6);
        int lane = threadIdx.x & 63;
        const v4f* xr = (const v4f*)(x + (size_t)gwave * IN);
        const v4f* dl = (const v4f*)dly;
        float acc = 0.0f;
        #pragma unroll
        for (int k = 0; k < 4; ++k) {
            int idx = k * 64 + lane;                       // 16B/lane, coalesced
            v4f xv = __builtin_nontemporal_load(xr + idx); // nt: bypass cache alloc
            v4f dv = dl[idx];
            acc += xv.x * dv.x + xv.y * dv.y + xv.z * dv.z + xv.w * dv.w;
        }
        #pragma unroll
        for (int off = 32; off; off >>= 1) acc += __shfl_xor(acc, off);
        if (lane == 0) {
            int b = gwave / T;
            int t = gwave - b * T;
            drive[t * B + b] = acc;
        }
    } else if (blk < NDRV + NW1D) {
        __shared__ float dly[64];
        int q = blk - NDRV;
        int hc = q >> 2, bb = q & 3;
        int h0 = hc * 64;
        if (threadIdx.x < 64)
            dly[threadIdx.x] = delay_of(lor, cd[h0 + threadIdx.x]);
        __syncthreads();
        int b = bb * 256 + threadIdx.x;
        float acc = 0.0f;
        #pragma unroll 8
        for (int k = 0; k < 64; ++k)
            acc += fc1_w[(size_t)(h0 + k) * IN + b] * dly[k];
        partial[hc * IN + b] = acc;
    } else {
        int gw = ((blk - NDRV - NW1D) * 256 + threadIdx.x) >> 6; // 512 waves -> OUT rows
        int lane = threadIdx.x & 63;
        const float4* r = (const float4*)(fc2_w + (size_t)gw * HID);
        float acc = 0.0f;
        #pragma unroll
        for (int k = 0; k < 4; ++k) {
            float4 v = r[k * 64 + lane];
            acc += v.x + v.y + v.z + v.w;
        }
        #pragma unroll
        for (int off = 32; off; off >>= 1) acc += __shfl_xor(acc, off);
        if (lane == 0) rowsum[gw] = acc;
    }
}

// single block, 1024 threads: c1 + w1d combine + chunked LIF scan + hm scan + output
__global__ __launch_bounds__(1024) void k_scan(const float* __restrict__ drive,
                                               const float* __restrict__ partial,
                                               const float* __restrict__ cd,
                                               const float* __restrict__ fc1_b,
                                               const float* __restrict__ fc2_b,
                                               const float* __restrict__ ta,
                                               const float* __restrict__ lor,
                                               const float* __restrict__ ibeta,
                                               const float* __restrict__ hbeta,
                                               const float* __restrict__ ithr,
                                               const float* __restrict__ hthr,
                                               const float* __restrict__ rowsum,
                                               float* __restrict__ out) {
    __shared__ float cbuf[16][B];   // 64 KB
    __shared__ float red[16];
    __shared__ float S[T];
    __shared__ float ta_l[T];
    __shared__ float sc[4];         // [0]=c1, [1]=wsum, [2]=tasum
    int b = threadIdx.x, wave = b >> 6, lane = b & 63;

    if (b < T) ta_l[b] = ta[b];

    float d = delay_of(lor, cd[b]);
    float c = fc1_b[b] * d;
    #pragma unroll
    for (int off = 32; off; off >>= 1) c += __shfl_xor(c, off);
    if (lane == 0) red[wave] = c;
    __syncthreads();
    if (b == 0) {
        float s = 0.0f;
        #pragma unroll
        for (int k = 0; k < 16; ++k) s += red[k];
        sc[0] = s;
    }

    float w = 0.0f;
    #pragma unroll
    for (int cc = 0; cc < 16; ++cc) w += partial[cc * IN + b];

    float ib = ibeta[0], it = ithr[0];
    float im = 0.0f;

    for (int t0 = 0; t0 < 96; t0 += 16) {
        #pragma unroll
        for (int tt = 0; tt < 16; ++tt) {
            im = im * ib + drive[(t0 + tt) * B + b];
            float isp = (im > it) ? 1.0f : 0.0f;
            im *= (1.0f - isp);
            cbuf[tt][b] = isp * w;
        }
        __syncthreads();
        {
            float s = 0.0f;
            #pragma unroll
            for (int k = 0; k < 16; ++k) s += cbuf[wave][lane + 64 * k];
            #pragma unroll
            for (int off = 32; off; off >>= 1) s += __shfl_xor(s, off);
            if (lane == 0) S[t0 + wave] = s + sc[0];
        }
        __syncthreads();
    }
    {
        #pragma unroll
        for (int tt = 0; tt < 4; ++tt) {
            im = im * ib + drive[(96 + tt) * B + b];
            float isp = (im > it) ? 1.0f : 0.0f;
            im *= (1.0f - isp);
            cbuf[tt][b] = isp * w;
        }
        __syncthreads();
        if (wave < 4) {
            float s = 0.0f;
            #pragma unroll
            for (int k = 0; k < 16; ++k) s += cbuf[wave][lane + 64 * k];
            #pragma unroll
            for (int off = 32; off; off >>= 1) s += __shfl_xor(s, off);
            if (lane == 0) S[96 + wave] = s + sc[0];
        }
        __syncthreads();
    }

    if (b == 0) {
        float hb = hbeta[0], ht = hthr[0];
        float hm = 0.0f, wsum = 0.0f, tasum = 0.0f;
        for (int t = 0; t < T; ++t) {
            hm = hm * hb + S[t];
            float hsp = (hm > ht) ? 1.0f : 0.0f;
            hm *= (1.0f - hsp);
            wsum += ta_l[t] * hsp;
            tasum += ta_l[t];
        }
        sc[1] = wsum; sc[2] = tasum;
    }
    __syncthreads();
    if (b < OUT) out[b] = sc[1] * rowsum[b] + sc[2] * fc2_b[b];
}

extern "C" void kernel_launch(void* const* d_in, const int* in_sizes, int n_in,
                              void* d_out, int out_size, void* d_ws, size_t ws_size,
                              hipStream_t stream) {
    const float* x      = (const float*)d_in[0];
    const float* cd     = (const float*)d_in[1];
    const float* fc1_w  = (const float*)d_in[2];
    const float* fc1_b  = (const float*)d_in[3];
    const float* fc2_w  = (const float*)d_in[4];
    const float* fc2_b  = (const float*)d_in[5];
    const float* ta     = (const float*)d_in[6];
    const float* lor    = (const float*)d_in[7];
    const float* ibeta  = (const float*)d_in[8];
    const float* hbeta  = (const float*)d_in[9];
    const float* ithr   = (const float*)d_in[10];
    const float* hthr   = (const float*)d_in[11];
    float* out = (float*)d_out;

    float* wsf     = (float*)d_ws;
    float* partial = wsf;
    float* rowsum  = wsf + 16384;
    float* drive   = wsf + 16896;

    k_main<<<NDRV + NW1D + NRSUM, 256, 0, stream>>>(x, cd, fc1_w, fc2_w, lor,
                                                    drive, partial, rowsum);
    k_scan<<<1, 1024, 0, stream>>>(drive, partial, cd, fc1_b, fc2_b, ta, lor,
                                   ibeta, hbeta, ithr, hthr, rowsum, out);
}